// Round 1
// baseline (248.340 us; speedup 1.0000x reference)
//
#include <hip/hip_runtime.h>
#include <math.h>

#define H 512
#define W 512
#define RM 8
#define TSX 32
#define TSY 8
#define LW (TSX + 2*RM)   // 48
#define LH (TSY + 2*RM)   // 24

#if defined(__has_builtin) && __has_builtin(__builtin_amdgcn_exp2f)
#define EXP2(x) __builtin_amdgcn_exp2f(x)
#else
#define EXP2(x) exp2f(x)
#endif

__global__ __launch_bounds__(256) void bilateral_kernel(
    const float* __restrict__ img, const float* __restrict__ params,
    float* __restrict__ out)
{
    __shared__ float lds[LH * LW * 3];

    const int n  = blockIdx.z;
    const int x0 = blockIdx.x * TSX;
    const int y0 = blockIdx.y * TSY;

    const float p0 = params[n*3 + 0];
    const float p1 = params[n*3 + 1];
    const float p2 = params[n*3 + 2];
    // window = int(p0)*14 + 3 ; radius = (window-1)/2
    const int win = ((int)p0) * 14 + 3;
    const int r   = (win - 1) >> 1;
    const float sc = fmaf(p1, 99.0f, 1.0f);
    const float ss = fmaf(p2, 99.0f, 1.0f);
    const float LOG2E = 1.4426950408889634f;
    // reference works on 255-scaled values; fold 255^2 and log2(e) into A
    const float A  = -65025.0f * LOG2E / (2.0f * sc * sc);
    const float Bs = -LOG2E / (2.0f * ss * ss);

    // ---- stage tile + halo into LDS as interleaved float3 (conflict-free) ----
    const float* imgN = img + (size_t)n * (3 * H * W);
    for (int idx = threadIdx.x; idx < LH * LW; idx += 256) {
        int ly = idx / LW;
        int lx = idx - ly * LW;
        int gy = y0 + ly - RM; gy = gy < 0 ? 0 : (gy > H-1 ? H-1 : gy);
        int gx = x0 + lx - RM; gx = gx < 0 ? 0 : (gx > W-1 ? W-1 : gx);
        int g = gy * W + gx;
        lds[idx*3 + 0] = imgN[g];
        lds[idx*3 + 1] = imgN[H*W + g];
        lds[idx*3 + 2] = imgN[2*H*W + g];
    }
    __syncthreads();

    // spatial-bias table; taps outside radius get -inf -> exp2 = 0 exactly,
    // matching the reference's where() mask with zero per-tap cost.
    float bx[2*RM + 1];
    #pragma unroll
    for (int i = 0; i <= 2*RM; ++i) {
        int d  = i - RM;
        int ad = d < 0 ? -d : d;
        bx[i] = (ad <= r) ? Bs * (float)(d*d) : -__builtin_inff();
    }

    const int tx = threadIdx.x & (TSX - 1);
    const int ty = threadIdx.x >> 5;

    const float* cent = &lds[((ty + RM) * LW + tx + RM) * 3];
    const float cr = cent[0], cg = cent[1], cb = cent[2];

    float nr = 0.0f, ng = 0.0f, nb = 0.0f, den = 0.0f;

    for (int dy = -RM; dy <= RM; ++dy) {
        int ady = dy < 0 ? -dy : dy;
        float by = (ady <= r) ? Bs * (float)(dy*dy) : -__builtin_inff();
        const float* row = &lds[((ty + RM + dy) * LW + tx) * 3];
        #pragma unroll
        for (int i = 0; i <= 2*RM; ++i) {
            float sr = row[3*i + 0];
            float sg = row[3*i + 1];
            float sb = row[3*i + 2];
            float dr = sr - cr, dg = sg - cg, db = sb - cb;
            float d2  = fmaf(db, db, fmaf(dg, dg, dr * dr));
            float arg = fmaf(d2, A, by + bx[i]);
            float w   = EXP2(arg);
            nr = fmaf(w, sr, nr);
            ng = fmaf(w, sg, ng);
            nb = fmaf(w, sb, nb);
            den += w;
        }
    }

    const float inv = __builtin_amdgcn_rcpf(den);
    const int o = (y0 + ty) * W + (x0 + tx);
    float* outN = out + (size_t)n * (3 * H * W);
    outN[o]         = nr * inv;
    outN[H*W + o]   = ng * inv;
    outN[2*H*W + o] = nb * inv;
}

extern "C" void kernel_launch(void* const* d_in, const int* in_sizes, int n_in,
                              void* d_out, int out_size, void* d_ws, size_t ws_size,
                              hipStream_t stream) {
    const float* img    = (const float*)d_in[0];
    const float* params = (const float*)d_in[1];
    float* out          = (float*)d_out;
    dim3 grid(W / TSX, H / TSY, 8);
    bilateral_kernel<<<grid, dim3(256), 0, stream>>>(img, params, out);
}